// Round 9
// baseline (273.587 us; speedup 1.0000x reference)
//
#include <hip/hip_runtime.h>

typedef unsigned short u16;
typedef __bf16 bf16x8 __attribute__((ext_vector_type(8)));
typedef float floatx4 __attribute__((ext_vector_type(4)));
typedef u16 u16x4 __attribute__((ext_vector_type(4)));

// fp32 -> bf16 via HW cvt (RNE, single VALU op; compiler packs pairs into
// v_cvt_pk_bf16_f32).
__device__ inline u16 f2bf(float x) {
    __bf16 b = (__bf16)x;
    return __builtin_bit_cast(u16, b);
}

__device__ inline floatx4 fzero() {
    floatx4 z = {0.f, 0.f, 0.f, 0.f};
    return z;
}

#if defined(__has_builtin)
#if __has_builtin(__builtin_amdgcn_exp2f)
#define EXP2F(x) __builtin_amdgcn_exp2f(x)
#endif
#endif
#ifndef EXP2F
#define EXP2F(x) exp2f(x)
#endif

// Load 8 contiguous elements as a bf16x8 fragment; fp32 source converts RNE.
template <bool F32>
__device__ inline bf16x8 ld8(const void* base, size_t off) {
    if constexpr (F32) {
        const float* p = (const float*)base + off;
        float4 a = *(const float4*)p;
        float4 b = *(const float4*)(p + 4);
        union { u16 u[8]; bf16x8 v; } t;
        t.u[0] = f2bf(a.x); t.u[1] = f2bf(a.y); t.u[2] = f2bf(a.z); t.u[3] = f2bf(a.w);
        t.u[4] = f2bf(b.x); t.u[5] = f2bf(b.y); t.u[6] = f2bf(b.z); t.u[7] = f2bf(b.w);
        return t.v;
    } else {
        return *(const bf16x8*)((const u16*)base + off);
    }
}

// Async global->LDS, 16B per lane. LDS dest MUST be wave-uniform; HW appends
// lane*16 itself (m104/m108). Callers pass the wave-uniform base only.
typedef __attribute__((address_space(1))) const unsigned int as1_u32;
typedef __attribute__((address_space(3))) unsigned int as3_u32;
__device__ inline void gld_lds16(const void* g, void* l) {
    __builtin_amdgcn_global_load_lds((as1_u32*)g, (as3_u32*)l, 16, 0, 0);
}

// XOR-swizzled LDS accessor for 64-el (128 B) rows.
// byte ^= (row&7)<<4 : bijective within each 8-row stripe, spreads the
// 16B slots of a column across all 8 slots -> conflict-free ds_read_b128.
__device__ inline u16* swz_ptr(u16* buf, int row, int col) {
    return (u16*)((char*)buf + row * 128 + ((col * 2) ^ ((row & 7) << 4)));
}

// ---------------------------------------------------------------------------
// fp32 -> bf16 bulk convert, ALL THREE tensors in one dispatch (dst regions
// are contiguous in the workspace: [XB | WAB | WPB]).
// ---------------------------------------------------------------------------
__global__ __launch_bounds__(256) void cvt_all(const float* __restrict__ x,
                                               const float* __restrict__ wa,
                                               const float* __restrict__ wp,
                                               u16* __restrict__ dst) {
    const int XB8 = 1048576, WAB8 = 393216;    // 8-el groups per tensor
    int i = blockIdx.x * 256 + threadIdx.x;    // grid covers exactly total
    const float* src; size_t off;
    if (i < XB8)             { src = x;  off = (size_t)i * 8; }
    else if (i < XB8 + WAB8) { src = wa; off = (size_t)(i - XB8) * 8; }
    else                     { src = wp; off = (size_t)(i - XB8 - WAB8) * 8; }
    *(bf16x8*)(dst + (size_t)i * 8) = ld8<true>(src, off);
}

// ---------------------------------------------------------------------------
// C[M,N] = A[M,K] * B[N,K]^T.
// bf16 path: minimum-2-phase double-buffer (T3).
// WVT: for V-region tiles (tn>=2048 of the QKV gemm), ALSO store the
// bf16-rounded C values transposed into vT [bh][dh][t] — fuses transpose_v
// into the epilogue (values identical: transpose_v also read post-rounding).
// ---------------------------------------------------------------------------
#define BK 32

template <bool AF32, bool BF32, bool CF32, bool WVT>
__global__ __launch_bounds__(256) void gemm_bt(const void* __restrict__ Ap,
                                               const void* __restrict__ Bp,
                                               void* __restrict__ Cp,
                                               u16* __restrict__ vtp,
                                               int M, int N, int K) {
    __shared__ alignas(16) u16 As[2][128 * BK];
    __shared__ alignas(16) u16 Bs[2][128 * BK];

    const int tid  = threadIdx.x;
    const int lane = tid & 63;
    const int wave = tid >> 6;
    const int wm = (wave >> 1) * 64;
    const int wn = (wave & 1) * 64;
    const int tm = blockIdx.y * 128;
    const int tn = blockIdx.x * 128;
    const int l15 = lane & 15;
    const int l4  = lane >> 4;

    const int srow = tid >> 2;
    const int scol = (tid & 3) * 8;

    floatx4 acc[4][4];
#pragma unroll
    for (int i = 0; i < 4; i++)
#pragma unroll
        for (int j = 0; j < 4; j++) acc[i][j] = fzero();

    if constexpr (!AF32 && !BF32) {
        // Per-lane GLOBAL source is allowed; LDS dest is the wave-uniform base,
        // HW writes lane l at base + l*16 -> LDS element tid*8 overall.
        const u16* Ag = (const u16*)Ap + (size_t)(tm + srow) * K + scol;
        const u16* Bg = (const u16*)Bp + (size_t)(tn + srow) * K + scol;

        auto stage = [&](int buf, int k0) {
            gld_lds16(Ag + k0,                  &As[buf][wave * 512]);
            gld_lds16(Ag + k0 + (size_t)64 * K, &As[buf][2048 + wave * 512]);
            gld_lds16(Bg + k0,                  &Bs[buf][wave * 512]);
            gld_lds16(Bg + k0 + (size_t)64 * K, &Bs[buf][2048 + wave * 512]);
        };

        stage(0, 0);
        __syncthreads();                       // prologue tile landed
        int cur = 0;
        const int nk = K / BK;
        for (int t = 0; t < nk; t++) {
            if (t + 1 < nk) stage(cur ^ 1, (t + 1) * BK);  // issue early

            bf16x8 af[4], bfv[4];
#pragma unroll
            for (int i = 0; i < 4; i++)
                af[i] = *(const bf16x8*)&As[cur][(wm + i * 16 + l15) * BK + l4 * 8];
#pragma unroll
            for (int j = 0; j < 4; j++)
                bfv[j] = *(const bf16x8*)&Bs[cur][(wn + j * 16 + l15) * BK + l4 * 8];
#pragma unroll
            for (int i = 0; i < 4; i++)
#pragma unroll
                for (int j = 0; j < 4; j++)
                    acc[i][j] = __builtin_amdgcn_mfma_f32_16x16x32_bf16(af[i], bfv[j], acc[i][j], 0, 0, 0);

            __syncthreads();                   // reads done + next tile landed
            cur ^= 1;
        }
    } else {
        for (int k0 = 0; k0 < K; k0 += BK) {
            bf16x8 av[2], bv[2];
#pragma unroll
            for (int q = 0; q < 2; q++) {
                av[q] = ld8<AF32>(Ap, (size_t)(tm + srow + q * 64) * K + k0 + scol);
                bv[q] = ld8<BF32>(Bp, (size_t)(tn + srow + q * 64) * K + k0 + scol);
            }
            __syncthreads();
#pragma unroll
            for (int q = 0; q < 2; q++) {
                *(bf16x8*)&As[0][(srow + q * 64) * BK + scol] = av[q];
                *(bf16x8*)&Bs[0][(srow + q * 64) * BK + scol] = bv[q];
            }
            __syncthreads();

            bf16x8 af[4], bfv[4];
#pragma unroll
            for (int i = 0; i < 4; i++)
                af[i] = *(const bf16x8*)&As[0][(wm + i * 16 + l15) * BK + l4 * 8];
#pragma unroll
            for (int j = 0; j < 4; j++)
                bfv[j] = *(const bf16x8*)&Bs[0][(wn + j * 16 + l15) * BK + l4 * 8];
#pragma unroll
            for (int i = 0; i < 4; i++)
#pragma unroll
                for (int j = 0; j < 4; j++)
                    acc[i][j] = __builtin_amdgcn_mfma_f32_16x16x32_bf16(af[i], bfv[j], acc[i][j], 0, 0, 0);
        }
    }

#pragma unroll
    for (int i = 0; i < 4; i++)
#pragma unroll
        for (int j = 0; j < 4; j++) {
            if constexpr (CF32) {
#pragma unroll
                for (int r = 0; r < 4; r++) {
                    int row = tm + wm + i * 16 + l4 * 4 + r;
                    int col = tn + wn + j * 16 + l15;
                    ((float*)Cp)[(size_t)row * N + col] = acc[i][j][r];
                }
            } else {
                u16 v4[4];
#pragma unroll
                for (int r = 0; r < 4; r++) v4[r] = f2bf(acc[i][j][r]);
#pragma unroll
                for (int r = 0; r < 4; r++) {
                    int row = tm + wm + i * 16 + l4 * 4 + r;
                    int col = tn + wn + j * 16 + l15;
                    ((u16*)Cp)[(size_t)row * N + col] = v4[r];
                }
                if constexpr (WVT) {
                    if (tn >= 2048) {          // V-region tile (block-uniform)
                        int row0 = tm + wm + i * 16 + l4 * 4;   // mult of 4
                        int colv = tn + wn + j * 16 + l15 - 2048;
                        int bh = (row0 >> 11) * 16 + (colv >> 6);
                        int dh = colv & 63;
                        int t  = row0 & 2047;
                        u16x4 w = {v4[0], v4[1], v4[2], v4[3]};
                        *(u16x4*)&vtp[(size_t)bh * 131072 + (size_t)dh * 2048 + t] = w;
                    }
                }
            }
        }
}

// ---------------------------------------------------------------------------
// Flash attention, causal, no online rescaling (scores bounded).
// 2x2 wave decomposition: wave (wq,wk) owns q-rows [wq*32,+32) x keys
// [wk*32,+32) of each tile -> K/V fragment reads per wave halved (the 4x
// cross-wave frag redundancy was the dominant LDS-BW term: 360->264 DS
// cyc/wave-tile).  All LDS patterns identical to measured-0-conflict ones;
// MFMA count unchanged (16x16x32 only).  One-time cross-wave O/L reduction
// through LDS (KP+Vt reused as f32 buffer).  Staging = verified r5 T14.
// ---------------------------------------------------------------------------
__global__ __launch_bounds__(256) void attn4(const u16* __restrict__ qkv,
                                             const u16* __restrict__ vT,
                                             u16* __restrict__ y) {
    const int T = 2048, CW = 3072;
    __shared__ alignas(16) u16 SMEM[3 * 64 * 64];   // 24 KB
    u16* KP = SMEM;                 // K tile [key][dh], swizzled
    u16* Vt = SMEM + 4096;          // V^T tile [dh][key], swizzled
    u16* PB = SMEM + 8192;          // P tile [q][key], swizzled, wave-private quads

    const int tid  = threadIdx.x;
    const int lane = tid & 63;
    const int wave = tid >> 6;
    const int wq = wave >> 1;                  // q-half owner
    const int wk = wave & 1;                   // key-half owner
    const int l15 = lane & 15;
    const int l4  = lane >> 4;

    const int bh = blockIdx.x;
    const int qt = 31 - blockIdx.y;            // heavy tiles dispatched first
    const int b = bh >> 4, h = bh & 15;
    const int q0 = qt * 64;
    const int qlo = q0 + wq * 32;              // wave's first q row (absolute)

    const size_t base = (size_t)b * T * CW + h * 64;
    const u16* qp = qkv + base;
    const u16* kp = qkv + base + 1024;
    const u16* vtp = vT + (size_t)bh * 131072;

    // Q fragments for the wave's 2 q-blocks
    bf16x8 qf[2][2];
#pragma unroll
    for (int qb = 0; qb < 2; qb++) {
        int qrow = qlo + qb * 16 + l15;
        qf[qb][0] = *(const bf16x8*)&qp[(size_t)qrow * CW + l4 * 8];
        qf[qb][1] = *(const bf16x8*)&qp[(size_t)qrow * CW + 32 + l4 * 8];
    }

    bf16x8 ones;
#pragma unroll
    for (int i = 0; i < 8; i++) ones[i] = (__bf16)1.0f;

    const float C2 = 0.18033688f;              // (1/8) * log2(e)
    floatx4 Lacc[2] = {fzero(), fzero()};      // partial rowsums (wave's 32 keys)
    floatx4 Oacc[2][4];
#pragma unroll
    for (int qb = 0; qb < 2; qb++)
#pragma unroll
        for (int cf = 0; cf < 4; cf++) Oacc[qb][cf] = fzero();

    const int sr = tid >> 3;                   // 0..31 (staging row)
    const int sc = tid & 7;                    // 0..7  (staging 16B chunk)

    bf16x8 kreg[2], vreg[2];
    auto stage_load = [&](int kt) {
        const int t0 = kt * 64;
#pragma unroll
        for (int p = 0; p < 2; p++)
            kreg[p] = *(const bf16x8*)&kp[(size_t)(t0 + sr + p * 32) * CW + sc * 8];
#pragma unroll
        for (int p = 0; p < 2; p++)
            vreg[p] = *(const bf16x8*)&vtp[(size_t)(sr + p * 32) * 2048 + t0 + sc * 8];
    };

    stage_load(0);

    for (int kt = 0; kt <= qt; kt++) {
        const int t0 = kt * 64;
        __syncthreads();                       // prev tile reads done

        // commit staged K/V (compiler waits vmcnt before these ds_writes)
#pragma unroll
        for (int p = 0; p < 2; p++)
            *(bf16x8*)swz_ptr(KP, sr + p * 32, sc * 8) = kreg[p];
#pragma unroll
        for (int p = 0; p < 2; p++)
            *(bf16x8*)swz_ptr(Vt, sr + p * 32, sc * 8) = vreg[p];
        __syncthreads();

        if (kt < qt) stage_load(kt + 1);       // prefetch next tile under compute

        const int kbase = t0 + wk * 32;        // wave's first key this tile
        if (kbase <= qlo + 31) {               // wave-uniform activity test
            // K fragments for the wave's 2 key-blocks (4 b128, was 8)
            bf16x8 kf[2][2];
#pragma unroll
            for (int kb = 0; kb < 2; kb++) {
                kf[kb][0] = *(const bf16x8*)swz_ptr(KP, wk * 32 + kb * 16 + l15, l4 * 8);
                kf[kb][1] = *(const bf16x8*)swz_ptr(KP, wk * 32 + kb * 16 + l15, 32 + l4 * 8);
            }
            const bool fast = (t0 + 63 <= qlo);    // whole tile below diagonal
#pragma unroll
            for (int qb = 0; qb < 2; qb++)
#pragma unroll
                for (int kb = 0; kb < 2; kb++) {
                    floatx4 s = fzero();
                    s = __builtin_amdgcn_mfma_f32_16x16x32_bf16(qf[qb][0], kf[kb][0], s, 0, 0, 0);
                    s = __builtin_amdgcn_mfma_f32_16x16x32_bf16(qf[qb][1], kf[kb][1], s, 0, 0, 0);
                    float pj[4];
                    if (fast) {
#pragma unroll
                        for (int r = 0; r < 4; r++) pj[r] = EXP2F(s[r] * C2);
                    } else {
#pragma unroll
                        for (int r = 0; r < 4; r++) {
                            int qrow = qlo + qb * 16 + l4 * 4 + r;
                            int krow = kbase + kb * 16 + l15;
                            float e = (krow <= qrow) ? s[r] * C2 : -1.0e30f;
                            pj[r] = EXP2F(e);
                        }
                    }
                    // wave-private P quadrant; same-wave DS ordering, no barrier
#pragma unroll
                    for (int r = 0; r < 4; r++)
                        *swz_ptr(PB, wq * 32 + qb * 16 + l4 * 4 + r,
                                 wk * 32 + kb * 16 + l15) = f2bf(pj[r]);
                }

            // P A-frags (wave's own quadrant) + denominator + PV
            bf16x8 pf[2];
#pragma unroll
            for (int qb = 0; qb < 2; qb++) {
                pf[qb] = *(const bf16x8*)swz_ptr(PB, wq * 32 + qb * 16 + l15, wk * 32 + l4 * 8);
                Lacc[qb] = __builtin_amdgcn_mfma_f32_16x16x32_bf16(pf[qb], ones, Lacc[qb], 0, 0, 0);
            }
#pragma unroll
            for (int cf = 0; cf < 4; cf++) {
                bf16x8 vb = *(const bf16x8*)swz_ptr(Vt, cf * 16 + l15, wk * 32 + l4 * 8);
#pragma unroll
                for (int qb = 0; qb < 2; qb++)
                    Oacc[qb][cf] = __builtin_amdgcn_mfma_f32_16x16x32_bf16(pf[qb], vb, Oacc[qb][cf], 0, 0, 0);
            }
        }
    }

    // ---- cross-wave (wk) reduction of O and L, then output ----
    __syncthreads();                           // last tile reads done; reuse KP+Vt
    float* Obuf = (float*)SMEM;                // [64 q][64 d] f32 (16 KB)
    float* Lbuf = (float*)(SMEM + 8192);       // 64 f32 (in PB region)
    if (wk == 1) {
#pragma unroll
        for (int qb = 0; qb < 2; qb++)
#pragma unroll
            for (int cf = 0; cf < 4; cf++)
#pragma unroll
                for (int r = 0; r < 4; r++)
                    Obuf[(wq * 32 + qb * 16 + l4 * 4 + r) * 64 + cf * 16 + l15] = Oacc[qb][cf][r];
        if (l15 == 0)
#pragma unroll
            for (int qb = 0; qb < 2; qb++)
#pragma unroll
                for (int r = 0; r < 4; r++)
                    Lbuf[wq * 32 + qb * 16 + l4 * 4 + r] = Lacc[qb][r];
    }
    __syncthreads();
    if (wk == 0) {
#pragma unroll
        for (int qb = 0; qb < 2; qb++)
#pragma unroll
            for (int r = 0; r < 4; r++) {
                int qr = wq * 32 + qb * 16 + l4 * 4 + r;
                float inv = 1.0f / (Lacc[qb][r] + Lbuf[qr]);
                size_t orow = ((size_t)b * T + q0 + qr) * 1024 + h * 64;
#pragma unroll
                for (int cf = 0; cf < 4; cf++) {
                    float o = Oacc[qb][cf][r] + Obuf[qr * 64 + cf * 16 + l15];
                    y[orow + cf * 16 + l15] = f2bf(o * inv);
                }
            }
    }
}

// ---------------------------------------------------------------------------
// Fallback attention (no vT workspace): r5 structure, scalar V gather.
// ---------------------------------------------------------------------------
__global__ __launch_bounds__(256) void attn2f(const u16* __restrict__ qkv,
                                              u16* __restrict__ y) {
    const int T = 2048, CW = 3072;
    __shared__ alignas(16) u16 KP[64 * 64];
    __shared__ alignas(16) u16 Vt[64 * 64];
    __shared__ alignas(16) u16 PB[64 * 64];

    const int tid  = threadIdx.x;
    const int lane = tid & 63;
    const int wave = tid >> 6;
    const int l15 = lane & 15;
    const int l4  = lane >> 4;

    const int bh = blockIdx.x;
    const int qt = 31 - blockIdx.y;
    const int b = bh >> 4, h = bh & 15;
    const int q0 = qt * 64;

    const size_t base = (size_t)b * T * CW + h * 64;
    const u16* qp = qkv + base;
    const u16* kp = qkv + base + 1024;
    const u16* vp = qkv + base + 2048;

    bf16x8 qf[2];
    {
        int qrow = q0 + wave * 16 + l15;
        qf[0] = *(const bf16x8*)&qp[(size_t)qrow * CW + l4 * 8];
        qf[1] = *(const bf16x8*)&qp[(size_t)qrow * CW + 32 + l4 * 8];
    }

    bf16x8 ones;
#pragma unroll
    for (int i = 0; i < 8; i++) ones[i] = (__bf16)1.0f;

    const float C2 = 0.18033688f;
    floatx4 Lacc = fzero();
    floatx4 Oacc[4];
#pragma unroll
    for (int cf = 0; cf < 4; cf++) Oacc[cf] = fzero();

    const int sr = tid >> 3;
    const int sc = tid & 7;

    bf16x8 kreg[2], vreg[2];
    auto stage_load = [&](int kt) {
        const int t0 = kt * 64;
#pragma unroll
        for (int p = 0; p < 2; p++)
            kreg[p] = *(const bf16x8*)&kp[(size_t)(t0 + sr + p * 32) * CW + sc * 8];
        const int dh = tid & 63;
        const int tb = wave * 8;
#pragma unroll
        for (int p = 0; p < 2; p++) {
            union { u16 u[8]; bf16x8 v; } tmp;
#pragma unroll
            for (int i = 0; i < 8; i++)
                tmp.u[i] = vp[(size_t)(t0 + tb + p * 32 + i) * CW + dh];
            vreg[p] = tmp.v;
        }
    };

    stage_load(0);

    for (int kt = 0; kt <= qt; kt++) {
        const int t0 = kt * 64;
        __syncthreads();
#pragma unroll
        for (int p = 0; p < 2; p++)
            *(bf16x8*)swz_ptr(KP, sr + p * 32, sc * 8) = kreg[p];
        {
            const int dh = tid & 63;
            const int tb = wave * 8;
#pragma unroll
            for (int p = 0; p < 2; p++)
                *(bf16x8*)swz_ptr(Vt, dh, tb + p * 32) = vreg[p];
        }
        __syncthreads();

        if (kt < qt) stage_load(kt + 1);

#pragma unroll
        for (int j = 0; j < 4; j++) {
            bf16x8 k0f = *(const bf16x8*)swz_ptr(KP, j * 16 + l15, l4 * 8);
            bf16x8 k1f = *(const bf16x8*)swz_ptr(KP, j * 16 + l15, 32 + l4 * 8);
            floatx4 s = fzero();
            s = __builtin_amdgcn_mfma_f32_16x16x32_bf16(qf[0], k0f, s, 0, 0, 0);
            s = __builtin_amdgcn_mfma_f32_16x16x32_bf16(qf[1], k1f, s, 0, 0, 0);
            float pj[4];
            if (kt == qt) {
#pragma unroll
                for (int r = 0; r < 4; r++) {
                    int qrow = q0 + wave * 16 + l4 * 4 + r;
                    int krow = t0 + j * 16 + l15;
                    float e = (krow <= qrow) ? s[r] * C2 : -1.0e30f;
                    pj[r] = EXP2F(e);
                }
            } else {
#pragma unroll
                for (int r = 0; r < 4; r++) pj[r] = EXP2F(s[r] * C2);
            }
#pragma unroll
            for (int r = 0; r < 4; r++)
                *swz_ptr(PB, wave * 16 + l4 * 4 + r, j * 16 + l15) = f2bf(pj[r]);
        }

        bf16x8 pf0 = *(const bf16x8*)swz_ptr(PB, wave * 16 + l15, l4 * 8);
        bf16x8 pf1 = *(const bf16x8*)swz_ptr(PB, wave * 16 + l15, 32 + l4 * 8);
        Lacc = __builtin_amdgcn_mfma_f32_16x16x32_bf16(pf0, ones, Lacc, 0, 0, 0);
        Lacc = __builtin_amdgcn_mfma_f32_16x16x32_bf16(pf1, ones, Lacc, 0, 0, 0);
#pragma unroll
        for (int cf = 0; cf < 4; cf++) {
            bf16x8 v0f = *(const bf16x8*)swz_ptr(Vt, cf * 16 + l15, l4 * 8);
            bf16x8 v1f = *(const bf16x8*)swz_ptr(Vt, cf * 16 + l15, 32 + l4 * 8);
            Oacc[cf] = __builtin_amdgcn_mfma_f32_16x16x32_bf16(pf0, v0f, Oacc[cf], 0, 0, 0);
            Oacc[cf] = __builtin_amdgcn_mfma_f32_16x16x32_bf16(pf1, v1f, Oacc[cf], 0, 0, 0);
        }
    }

#pragma unroll
    for (int r = 0; r < 4; r++) {
        float inv = 1.0f / Lacc[r];
        int qrow = q0 + wave * 16 + l4 * 4 + r;
        size_t orow = ((size_t)b * T + qrow) * 1024 + h * 64;
#pragma unroll
        for (int cf = 0; cf < 4; cf++)
            y[orow + cf * 16 + l15] = f2bf(Oacc[cf][r] * inv);
    }
}

extern "C" void kernel_launch(void* const* d_in, const int* in_sizes, int n_in,
                              void* d_out, int out_size, void* d_ws, size_t ws_size,
                              hipStream_t stream) {
    const float* x      = (const float*)d_in[0];   // [8192,1024] fp32
    const float* w_attn = (const float*)d_in[1];   // [3072,1024] fp32
    const float* w_proj = (const float*)d_in[2];   // [1024,1024] fp32
    float* out = (float*)d_out;                    // [8192,1024] fp32

    const size_t QKV = (size_t)8192 * 3072;
    const size_t Y   = (size_t)8192 * 1024;
    const size_t VTE = (size_t)64 * 64 * 2048;     // 8.4M
    const size_t XB  = (size_t)8192 * 1024;
    const size_t WAB = (size_t)3072 * 1024;
    const size_t WPB = (size_t)1024 * 1024;

    u16* qkv = (u16*)d_ws;
    u16* yb  = qkv + QKV;

    const bool full = ws_size >= (QKV + Y + VTE + XB + WAB + WPB) * sizeof(u16); // 104 MiB
    if (ws_size < (QKV + Y) * sizeof(u16)) return;                               // 64 MiB floor

    dim3 blk(256);
    dim3 g1(3072 / 128, 8192 / 128), g2(1024 / 128, 8192 / 128);
    dim3 ga(64, 32);

    if (full) {
        u16* vT  = yb + Y;
        u16* xb  = vT + VTE;                       // xb|wab|wpb contiguous
        cvt_all<<<6144, blk, 0, stream>>>(x, w_attn, w_proj, xb);
        u16* wab = xb + XB;
        u16* wpb = wab + WAB;
        // gemm1 writes qkv AND the transposed V copy (fused transpose_v)
        gemm_bt<false, false, false, true><<<g1, blk, 0, stream>>>(xb, wab, qkv, vT, 8192, 3072, 1024);
        attn4<<<ga, blk, 0, stream>>>(qkv, vT, yb);
        gemm_bt<false, false, true, false><<<g2, blk, 0, stream>>>(yb, wpb, out, nullptr, 8192, 1024, 1024);
    } else {
        gemm_bt<true, true, false, false><<<g1, blk, 0, stream>>>(x, w_attn, qkv, nullptr, 8192, 3072, 1024);
        attn2f<<<ga, blk, 0, stream>>>(qkv, yb);
        gemm_bt<false, true, true, false><<<g2, blk, 0, stream>>>(yb, w_proj, out, nullptr, 8192, 1024, 1024);
    }
}

// Round 10
// 252.174 us; speedup vs baseline: 1.0849x; 1.0849x over previous
//
#include <hip/hip_runtime.h>

typedef unsigned short u16;
typedef __bf16 bf16x8 __attribute__((ext_vector_type(8)));
typedef float floatx4 __attribute__((ext_vector_type(4)));
typedef u16 u16x4 __attribute__((ext_vector_type(4)));

// fp32 -> bf16 via HW cvt (RNE, single VALU op; compiler packs pairs into
// v_cvt_pk_bf16_f32).
__device__ inline u16 f2bf(float x) {
    __bf16 b = (__bf16)x;
    return __builtin_bit_cast(u16, b);
}

__device__ inline floatx4 fzero() {
    floatx4 z = {0.f, 0.f, 0.f, 0.f};
    return z;
}

#if defined(__has_builtin)
#if __has_builtin(__builtin_amdgcn_exp2f)
#define EXP2F(x) __builtin_amdgcn_exp2f(x)
#endif
#endif
#ifndef EXP2F
#define EXP2F(x) exp2f(x)
#endif

// Load 8 contiguous elements as a bf16x8 fragment; fp32 source converts RNE.
template <bool F32>
__device__ inline bf16x8 ld8(const void* base, size_t off) {
    if constexpr (F32) {
        const float* p = (const float*)base + off;
        float4 a = *(const float4*)p;
        float4 b = *(const float4*)(p + 4);
        union { u16 u[8]; bf16x8 v; } t;
        t.u[0] = f2bf(a.x); t.u[1] = f2bf(a.y); t.u[2] = f2bf(a.z); t.u[3] = f2bf(a.w);
        t.u[4] = f2bf(b.x); t.u[5] = f2bf(b.y); t.u[6] = f2bf(b.z); t.u[7] = f2bf(b.w);
        return t.v;
    } else {
        return *(const bf16x8*)((const u16*)base + off);
    }
}

// Async global->LDS, 16B per lane. LDS dest MUST be wave-uniform; HW appends
// lane*16 itself (m104/m108). Callers pass the wave-uniform base only.
typedef __attribute__((address_space(1))) const unsigned int as1_u32;
typedef __attribute__((address_space(3))) unsigned int as3_u32;
__device__ inline void gld_lds16(const void* g, void* l) {
    __builtin_amdgcn_global_load_lds((as1_u32*)g, (as3_u32*)l, 16, 0, 0);
}

// XOR-swizzled LDS accessor for 64-el (128 B) rows.
// byte ^= (row&7)<<4 : bijective within each 8-row stripe, spreads the
// 16B slots of a column across all 8 slots -> conflict-free ds_read_b128.
__device__ inline u16* swz_ptr(u16* buf, int row, int col) {
    return (u16*)((char*)buf + row * 128 + ((col * 2) ^ ((row & 7) << 4)));
}

// ---------------------------------------------------------------------------
// fp32 -> bf16 bulk convert, ALL THREE tensors in one dispatch (dst regions
// are contiguous in the workspace: [XB | WAB | WPB]).
// ---------------------------------------------------------------------------
__global__ __launch_bounds__(256) void cvt_all(const float* __restrict__ x,
                                               const float* __restrict__ wa,
                                               const float* __restrict__ wp,
                                               u16* __restrict__ dst) {
    const int XB8 = 1048576, WAB8 = 393216;    // 8-el groups per tensor
    int i = blockIdx.x * 256 + threadIdx.x;    // grid covers exactly total
    const float* src; size_t off;
    if (i < XB8)             { src = x;  off = (size_t)i * 8; }
    else if (i < XB8 + WAB8) { src = wa; off = (size_t)(i - XB8) * 8; }
    else                     { src = wp; off = (size_t)(i - XB8 - WAB8) * 8; }
    *(bf16x8*)(dst + (size_t)i * 8) = ld8<true>(src, off);
}

// ---------------------------------------------------------------------------
// C[M,N] = A[M,K] * B[N,K]^T.
// bf16 path: minimum-2-phase double-buffer (T3).
// XCD-chunked blockIdx swizzle (T1, bijective since nwg%8==0): each XCD's
// blocks cover 8 CONTIGUOUS A row-panels -> A panel fetched into 1 L2, not 8.
// WVT: for V-region tiles (tn>=2048), also store bf16-rounded C transposed
// into vT [bh][dh][t] (fused transpose_v; values identical).
// ---------------------------------------------------------------------------
#define BK 32

template <bool AF32, bool BF32, bool CF32, bool WVT>
__global__ __launch_bounds__(256) void gemm_bt(const void* __restrict__ Ap,
                                               const void* __restrict__ Bp,
                                               void* __restrict__ Cp,
                                               u16* __restrict__ vtp,
                                               int M, int N, int K) {
    __shared__ alignas(16) u16 As[2][128 * BK];
    __shared__ alignas(16) u16 Bs[2][128 * BK];

    const int tid  = threadIdx.x;
    const int lane = tid & 63;
    const int wave = tid >> 6;
    const int wm = (wave >> 1) * 64;
    const int wn = (wave & 1) * 64;

    // T1 swizzle: orig id's XCD = id%8; give XCD k the contiguous tile range
    // [k*cpx, (k+1)*cpx) of row-major (tm,tn) space.
    const int gx = gridDim.x;
    int bid = blockIdx.y * gx + blockIdx.x;
    const int cpx = (gx * gridDim.y) >> 3;     // nwg % 8 == 0 (launcher invariant)
    bid = (bid & 7) * cpx + (bid >> 3);
    const int tm = (bid / gx) * 128;
    const int tn = (bid % gx) * 128;

    const int l15 = lane & 15;
    const int l4  = lane >> 4;

    const int srow = tid >> 2;
    const int scol = (tid & 3) * 8;

    floatx4 acc[4][4];
#pragma unroll
    for (int i = 0; i < 4; i++)
#pragma unroll
        for (int j = 0; j < 4; j++) acc[i][j] = fzero();

    if constexpr (!AF32 && !BF32) {
        // Per-lane GLOBAL source is allowed; LDS dest is the wave-uniform base,
        // HW writes lane l at base + l*16 -> LDS element tid*8 overall.
        const u16* Ag = (const u16*)Ap + (size_t)(tm + srow) * K + scol;
        const u16* Bg = (const u16*)Bp + (size_t)(tn + srow) * K + scol;

        auto stage = [&](int buf, int k0) {
            gld_lds16(Ag + k0,                  &As[buf][wave * 512]);
            gld_lds16(Ag + k0 + (size_t)64 * K, &As[buf][2048 + wave * 512]);
            gld_lds16(Bg + k0,                  &Bs[buf][wave * 512]);
            gld_lds16(Bg + k0 + (size_t)64 * K, &Bs[buf][2048 + wave * 512]);
        };

        stage(0, 0);
        __syncthreads();                       // prologue tile landed
        int cur = 0;
        const int nk = K / BK;
        for (int t = 0; t < nk; t++) {
            if (t + 1 < nk) stage(cur ^ 1, (t + 1) * BK);  // issue early

            bf16x8 af[4], bfv[4];
#pragma unroll
            for (int i = 0; i < 4; i++)
                af[i] = *(const bf16x8*)&As[cur][(wm + i * 16 + l15) * BK + l4 * 8];
#pragma unroll
            for (int j = 0; j < 4; j++)
                bfv[j] = *(const bf16x8*)&Bs[cur][(wn + j * 16 + l15) * BK + l4 * 8];
#pragma unroll
            for (int i = 0; i < 4; i++)
#pragma unroll
                for (int j = 0; j < 4; j++)
                    acc[i][j] = __builtin_amdgcn_mfma_f32_16x16x32_bf16(af[i], bfv[j], acc[i][j], 0, 0, 0);

            __syncthreads();                   // reads done + next tile landed
            cur ^= 1;
        }
    } else {
        for (int k0 = 0; k0 < K; k0 += BK) {
            bf16x8 av[2], bv[2];
#pragma unroll
            for (int q = 0; q < 2; q++) {
                av[q] = ld8<AF32>(Ap, (size_t)(tm + srow + q * 64) * K + k0 + scol);
                bv[q] = ld8<BF32>(Bp, (size_t)(tn + srow + q * 64) * K + k0 + scol);
            }
            __syncthreads();
#pragma unroll
            for (int q = 0; q < 2; q++) {
                *(bf16x8*)&As[0][(srow + q * 64) * BK + scol] = av[q];
                *(bf16x8*)&Bs[0][(srow + q * 64) * BK + scol] = bv[q];
            }
            __syncthreads();

            bf16x8 af[4], bfv[4];
#pragma unroll
            for (int i = 0; i < 4; i++)
                af[i] = *(const bf16x8*)&As[0][(wm + i * 16 + l15) * BK + l4 * 8];
#pragma unroll
            for (int j = 0; j < 4; j++)
                bfv[j] = *(const bf16x8*)&Bs[0][(wn + j * 16 + l15) * BK + l4 * 8];
#pragma unroll
            for (int i = 0; i < 4; i++)
#pragma unroll
                for (int j = 0; j < 4; j++)
                    acc[i][j] = __builtin_amdgcn_mfma_f32_16x16x32_bf16(af[i], bfv[j], acc[i][j], 0, 0, 0);
        }
    }

#pragma unroll
    for (int i = 0; i < 4; i++)
#pragma unroll
        for (int j = 0; j < 4; j++) {
            if constexpr (CF32) {
#pragma unroll
                for (int r = 0; r < 4; r++) {
                    int row = tm + wm + i * 16 + l4 * 4 + r;
                    int col = tn + wn + j * 16 + l15;
                    ((float*)Cp)[(size_t)row * N + col] = acc[i][j][r];
                }
            } else {
                u16 v4[4];
#pragma unroll
                for (int r = 0; r < 4; r++) v4[r] = f2bf(acc[i][j][r]);
#pragma unroll
                for (int r = 0; r < 4; r++) {
                    int row = tm + wm + i * 16 + l4 * 4 + r;
                    int col = tn + wn + j * 16 + l15;
                    ((u16*)Cp)[(size_t)row * N + col] = v4[r];
                }
                if constexpr (WVT) {
                    if (tn >= 2048) {          // V-region tile (block-uniform)
                        int row0 = tm + wm + i * 16 + l4 * 4;   // mult of 4
                        int colv = tn + wn + j * 16 + l15 - 2048;
                        int bh = (row0 >> 11) * 16 + (colv >> 6);
                        int dh = colv & 63;
                        int t  = row0 & 2047;
                        u16x4 w = {v4[0], v4[1], v4[2], v4[3]};
                        *(u16x4*)&vtp[(size_t)bh * 131072 + (size_t)dh * 2048 + t] = w;
                    }
                }
            }
        }
}

// ---------------------------------------------------------------------------
// Flash attention, causal, no online rescaling (scores bounded). Verified
// r5/r8 structure (74.6 us, 0 bank conflicts): single-buffer KP/Vt/PB,
// reg-staged K/V (T14), MFMA row-sum denominator, HW bf16 casts.
// This round adds only T5: s_setprio(1) around the L/PV MFMA cluster.
// ---------------------------------------------------------------------------
template <bool USE_VT>
__global__ __launch_bounds__(256) void attn2(const u16* __restrict__ qkv,
                                             const u16* __restrict__ vT,
                                             u16* __restrict__ y) {
    const int T = 2048, CW = 3072;
    __shared__ alignas(16) u16 KP[64 * 64];   // K tile [key][dh]
    __shared__ alignas(16) u16 Vt[64 * 64];   // V^T tile [dh][key]
    __shared__ alignas(16) u16 PB[64 * 64];   // P tile [qrow][key], wave-private rows

    const int tid  = threadIdx.x;
    const int lane = tid & 63;
    const int wave = tid >> 6;
    const int l15 = lane & 15;
    const int l4  = lane >> 4;

    const int bh = blockIdx.x;
    const int qt = 31 - blockIdx.y;            // heavy tiles dispatched first
    const int b = bh >> 4, h = bh & 15;
    const int q0 = qt * 64;

    const size_t base = (size_t)b * T * CW + h * 64;
    const u16* qp = qkv + base;
    const u16* kp = qkv + base + 1024;
    const u16* vp = qkv + base + 2048;
    const u16* vtp = USE_VT ? (vT + (size_t)bh * 131072) : nullptr;

    bf16x8 qf[2];
    {
        int qrow = q0 + wave * 16 + l15;
        qf[0] = *(const bf16x8*)&qp[(size_t)qrow * CW + l4 * 8];
        qf[1] = *(const bf16x8*)&qp[(size_t)qrow * CW + 32 + l4 * 8];
    }

    // all-ones B-fragment for the denominator MFMA
    bf16x8 ones;
#pragma unroll
    for (int i = 0; i < 8; i++) ones[i] = (__bf16)1.0f;

    const float C2 = 0.18033688f;              // (1/8) * log2(e)
    floatx4 Lacc = fzero();                    // rowsum accumulator
    floatx4 Oacc[4];
#pragma unroll
    for (int cf = 0; cf < 4; cf++) Oacc[cf] = fzero();

    const int sr = tid >> 3;                   // 0..31 (staging row)
    const int sc = tid & 7;                    // 0..7  (staging 16B chunk)

    bf16x8 kreg[2], vreg[2];
    auto stage_load = [&](int kt) {
        const int t0 = kt * 64;
#pragma unroll
        for (int p = 0; p < 2; p++)
            kreg[p] = *(const bf16x8*)&kp[(size_t)(t0 + sr + p * 32) * CW + sc * 8];
        if constexpr (USE_VT) {
#pragma unroll
            for (int p = 0; p < 2; p++)
                vreg[p] = *(const bf16x8*)&vtp[(size_t)(sr + p * 32) * 2048 + t0 + sc * 8];
        } else {
            const int dh = tid & 63;
            const int tb = wave * 8;
#pragma unroll
            for (int p = 0; p < 2; p++) {
                union { u16 u[8]; bf16x8 v; } tmp;
#pragma unroll
                for (int i = 0; i < 8; i++)
                    tmp.u[i] = vp[(size_t)(t0 + tb + p * 32 + i) * CW + dh];
                vreg[p] = tmp.v;
            }
        }
    };

    stage_load(0);

    for (int kt = 0; kt <= qt; kt++) {
        const int t0 = kt * 64;
        __syncthreads();                       // all waves' KP/Vt reads of prev tile done

        // commit staged K/V (compiler waits vmcnt before these ds_writes)
#pragma unroll
        for (int p = 0; p < 2; p++)
            *(bf16x8*)swz_ptr(KP, sr + p * 32, sc * 8) = kreg[p];
        if constexpr (USE_VT) {
#pragma unroll
            for (int p = 0; p < 2; p++)
                *(bf16x8*)swz_ptr(Vt, sr + p * 32, sc * 8) = vreg[p];
        } else {
            const int dh = tid & 63;
            const int tb = wave * 8;
#pragma unroll
            for (int p = 0; p < 2; p++)
                *(bf16x8*)swz_ptr(Vt, dh, tb + p * 32) = vreg[p];
        }
        __syncthreads();

        if (kt < qt) stage_load(kt + 1);       // prefetch next tile under compute

        // S = Q*K^T, per 16-key block: mask, exp2, P-store (short live ranges)
#pragma unroll
        for (int j = 0; j < 4; j++) {
            bf16x8 k0f = *(const bf16x8*)swz_ptr(KP, j * 16 + l15, l4 * 8);
            bf16x8 k1f = *(const bf16x8*)swz_ptr(KP, j * 16 + l15, 32 + l4 * 8);
            floatx4 s = fzero();
            s = __builtin_amdgcn_mfma_f32_16x16x32_bf16(qf[0], k0f, s, 0, 0, 0);
            s = __builtin_amdgcn_mfma_f32_16x16x32_bf16(qf[1], k1f, s, 0, 0, 0);
            float pj[4];
            if (kt == qt) {
#pragma unroll
                for (int r = 0; r < 4; r++) {
                    int qrow = q0 + wave * 16 + l4 * 4 + r;
                    int krow = t0 + j * 16 + l15;
                    float e = (krow <= qrow) ? s[r] * C2 : -1.0e30f;
                    pj[r] = EXP2F(e);
                }
            } else {
#pragma unroll
                for (int r = 0; r < 4; r++) pj[r] = EXP2F(s[r] * C2);
            }
            // wave-private rows; same-wave DS ordering -> no barrier needed
#pragma unroll
            for (int r = 0; r < 4; r++)
                *swz_ptr(PB, wave * 16 + l4 * 4 + r, j * 16 + l15) = f2bf(pj[r]);
        }

        // P A-frags (this wave's own 16 rows) + denominator + PV (T5 cluster)
        bf16x8 pf0 = *(const bf16x8*)swz_ptr(PB, wave * 16 + l15, l4 * 8);
        bf16x8 pf1 = *(const bf16x8*)swz_ptr(PB, wave * 16 + l15, 32 + l4 * 8);
        __builtin_amdgcn_s_setprio(1);
        Lacc = __builtin_amdgcn_mfma_f32_16x16x32_bf16(pf0, ones, Lacc, 0, 0, 0);
        Lacc = __builtin_amdgcn_mfma_f32_16x16x32_bf16(pf1, ones, Lacc, 0, 0, 0);
#pragma unroll
        for (int cf = 0; cf < 4; cf++) {
            bf16x8 v0f = *(const bf16x8*)swz_ptr(Vt, cf * 16 + l15, l4 * 8);
            bf16x8 v1f = *(const bf16x8*)swz_ptr(Vt, cf * 16 + l15, 32 + l4 * 8);
            Oacc[cf] = __builtin_amdgcn_mfma_f32_16x16x32_bf16(pf0, v0f, Oacc[cf], 0, 0, 0);
            Oacc[cf] = __builtin_amdgcn_mfma_f32_16x16x32_bf16(pf1, v1f, Oacc[cf], 0, 0, 0);
        }
        __builtin_amdgcn_s_setprio(0);
    }

    // epilogue: Lacc[r] already holds the full row sum in every lane column
#pragma unroll
    for (int r = 0; r < 4; r++) {
        float inv = 1.0f / Lacc[r];
        int qrow = q0 + wave * 16 + l4 * 4 + r;
        size_t orow = ((size_t)b * T + qrow) * 1024 + h * 64;
#pragma unroll
        for (int cf = 0; cf < 4; cf++)
            y[orow + cf * 16 + l15] = f2bf(Oacc[cf][r] * inv);
    }
}

extern "C" void kernel_launch(void* const* d_in, const int* in_sizes, int n_in,
                              void* d_out, int out_size, void* d_ws, size_t ws_size,
                              hipStream_t stream) {
    const float* x      = (const float*)d_in[0];   // [8192,1024] fp32
    const float* w_attn = (const float*)d_in[1];   // [3072,1024] fp32
    const float* w_proj = (const float*)d_in[2];   // [1024,1024] fp32
    float* out = (float*)d_out;                    // [8192,1024] fp32

    const size_t QKV = (size_t)8192 * 3072;
    const size_t Y   = (size_t)8192 * 1024;
    const size_t VTE = (size_t)64 * 64 * 2048;     // 8.4M
    const size_t XB  = (size_t)8192 * 1024;
    const size_t WAB = (size_t)3072 * 1024;
    const size_t WPB = (size_t)1024 * 1024;

    u16* qkv = (u16*)d_ws;
    u16* yb  = qkv + QKV;

    const bool full = ws_size >= (QKV + Y + VTE + XB + WAB + WPB) * sizeof(u16); // 104 MiB
    if (ws_size < (QKV + Y) * sizeof(u16)) return;                               // 64 MiB floor

    dim3 blk(256);
    dim3 g1(3072 / 128, 8192 / 128), g2(1024 / 128, 8192 / 128);   // nwg: 1536, 512 (both %8==0)
    dim3 ga(64, 32);

    if (full) {
        u16* vT  = yb + Y;
        u16* xb  = vT + VTE;                       // xb|wab|wpb contiguous
        cvt_all<<<6144, blk, 0, stream>>>(x, w_attn, w_proj, xb);
        u16* wab = xb + XB;
        u16* wpb = wab + WAB;
        // gemm1 writes qkv AND the transposed V copy (fused transpose_v)
        gemm_bt<false, false, false, true><<<g1, blk, 0, stream>>>(xb, wab, qkv, vT, 8192, 3072, 1024);
        attn2<true><<<ga, blk, 0, stream>>>(qkv, vT, yb);
        gemm_bt<false, false, true, false><<<g2, blk, 0, stream>>>(yb, wpb, out, nullptr, 8192, 1024, 1024);
    } else {
        gemm_bt<true, true, false, false><<<g1, blk, 0, stream>>>(x, w_attn, qkv, nullptr, 8192, 3072, 1024);
        attn2<false><<<ga, blk, 0, stream>>>(qkv, nullptr, yb);
        gemm_bt<false, true, true, false><<<g2, blk, 0, stream>>>(yb, w_proj, out, nullptr, 8192, 1024, 1024);
    }
}

// Round 11
// 250.019 us; speedup vs baseline: 1.0943x; 1.0086x over previous
//
#include <hip/hip_runtime.h>

typedef unsigned short u16;
typedef __bf16 bf16x8 __attribute__((ext_vector_type(8)));
typedef float floatx4 __attribute__((ext_vector_type(4)));
typedef u16 u16x4 __attribute__((ext_vector_type(4)));

// fp32 -> bf16 via HW cvt (RNE, single VALU op; compiler packs pairs into
// v_cvt_pk_bf16_f32).
__device__ inline u16 f2bf(float x) {
    __bf16 b = (__bf16)x;
    return __builtin_bit_cast(u16, b);
}

__device__ inline floatx4 fzero() {
    floatx4 z = {0.f, 0.f, 0.f, 0.f};
    return z;
}

#if defined(__has_builtin)
#if __has_builtin(__builtin_amdgcn_exp2f)
#define EXP2F(x) __builtin_amdgcn_exp2f(x)
#endif
#endif
#ifndef EXP2F
#define EXP2F(x) exp2f(x)
#endif

// Load 8 contiguous elements as a bf16x8 fragment; fp32 source converts RNE.
template <bool F32>
__device__ inline bf16x8 ld8(const void* base, size_t off) {
    if constexpr (F32) {
        const float* p = (const float*)base + off;
        float4 a = *(const float4*)p;
        float4 b = *(const float4*)(p + 4);
        union { u16 u[8]; bf16x8 v; } t;
        t.u[0] = f2bf(a.x); t.u[1] = f2bf(a.y); t.u[2] = f2bf(a.z); t.u[3] = f2bf(a.w);
        t.u[4] = f2bf(b.x); t.u[5] = f2bf(b.y); t.u[6] = f2bf(b.z); t.u[7] = f2bf(b.w);
        return t.v;
    } else {
        return *(const bf16x8*)((const u16*)base + off);
    }
}

// Async global->LDS, 16B per lane. LDS dest MUST be wave-uniform; HW appends
// lane*16 itself (m104/m108). Callers pass the wave-uniform base only.
typedef __attribute__((address_space(1))) const unsigned int as1_u32;
typedef __attribute__((address_space(3))) unsigned int as3_u32;
__device__ inline void gld_lds16(const void* g, void* l) {
    __builtin_amdgcn_global_load_lds((as1_u32*)g, (as3_u32*)l, 16, 0, 0);
}

// XOR-swizzled LDS accessor for 64-el (128 B) rows.
// byte ^= (row&7)<<4 : bijective within each 8-row stripe, spreads the
// 16B slots of a column across all 8 slots -> conflict-free ds_read_b128.
__device__ inline u16* swz_ptr(u16* buf, int row, int col) {
    return (u16*)((char*)buf + row * 128 + ((col * 2) ^ ((row & 7) << 4)));
}

// ---------------------------------------------------------------------------
// fp32 -> bf16 bulk convert, ALL THREE tensors in one dispatch (dst regions
// are contiguous in the workspace: [XB | WAB | WPB]).
// ---------------------------------------------------------------------------
__global__ __launch_bounds__(256) void cvt_all(const float* __restrict__ x,
                                               const float* __restrict__ wa,
                                               const float* __restrict__ wp,
                                               u16* __restrict__ dst) {
    const int XB8 = 1048576, WAB8 = 393216;    // 8-el groups per tensor
    int i = blockIdx.x * 256 + threadIdx.x;    // grid covers exactly total
    const float* src; size_t off;
    if (i < XB8)             { src = x;  off = (size_t)i * 8; }
    else if (i < XB8 + WAB8) { src = wa; off = (size_t)(i - XB8) * 8; }
    else                     { src = wp; off = (size_t)(i - XB8 - WAB8) * 8; }
    *(bf16x8*)(dst + (size_t)i * 8) = ld8<true>(src, off);
}

// ---------------------------------------------------------------------------
// C[M,N] = A[M,K] * B[N,K]^T.
// bf16 path: T4 counted-vmcnt pipeline on the 128x128/BK=32 geometry.
//   tile t lives in buf t&1; loads for tile t+2 are issued at the END of
//   iteration t, so each tile's loads get a FULL iteration to land.
//   Per iteration: [vmcnt(4)+s_barrier] frag-reads+MFMA [lgkmcnt(0)+s_barrier]
//   issue t+2.  No vmcnt(0) drain in the steady state (T4, m218).
// XCD-chunked blockIdx swizzle (T1, bijective since nwg%8==0).
// WVT: for V-region tiles (tn>=2048), also store bf16-rounded C transposed
// into vT [bh][dh][t] (fused transpose_v; values identical).
// ---------------------------------------------------------------------------
#define BK 32

template <bool AF32, bool BF32, bool CF32, bool WVT>
__global__ __launch_bounds__(256) void gemm_bt(const void* __restrict__ Ap,
                                               const void* __restrict__ Bp,
                                               void* __restrict__ Cp,
                                               u16* __restrict__ vtp,
                                               int M, int N, int K) {
    __shared__ alignas(16) u16 As[2][128 * BK];
    __shared__ alignas(16) u16 Bs[2][128 * BK];

    const int tid  = threadIdx.x;
    const int lane = tid & 63;
    const int wave = tid >> 6;
    const int wm = (wave >> 1) * 64;
    const int wn = (wave & 1) * 64;

    // T1 swizzle: orig id's XCD = id%8; give XCD k the contiguous tile range
    // [k*cpx, (k+1)*cpx) of row-major (tm,tn) space.
    const int gx = gridDim.x;
    int bid = blockIdx.y * gx + blockIdx.x;
    const int cpx = (gx * gridDim.y) >> 3;     // nwg % 8 == 0 (launcher invariant)
    bid = (bid & 7) * cpx + (bid >> 3);
    const int tm = (bid / gx) * 128;
    const int tn = (bid % gx) * 128;

    const int l15 = lane & 15;
    const int l4  = lane >> 4;

    const int srow = tid >> 2;
    const int scol = (tid & 3) * 8;

    floatx4 acc[4][4];
#pragma unroll
    for (int i = 0; i < 4; i++)
#pragma unroll
        for (int j = 0; j < 4; j++) acc[i][j] = fzero();

    if constexpr (!AF32 && !BF32) {
        // Per-lane GLOBAL source is allowed; LDS dest is the wave-uniform base,
        // HW writes lane l at base + l*16 -> LDS element tid*8 overall.
        const u16* Ag = (const u16*)Ap + (size_t)(tm + srow) * K + scol;
        const u16* Bg = (const u16*)Bp + (size_t)(tn + srow) * K + scol;

        auto stage = [&](int buf, int k0) {    // 4 vmcnt events
            gld_lds16(Ag + k0,                  &As[buf][wave * 512]);
            gld_lds16(Ag + k0 + (size_t)64 * K, &As[buf][2048 + wave * 512]);
            gld_lds16(Bg + k0,                  &Bs[buf][wave * 512]);
            gld_lds16(Bg + k0 + (size_t)64 * K, &Bs[buf][2048 + wave * 512]);
        };

        const int nk = K / BK;                 // >= 2 for all our shapes
        stage(0, 0);                           // tile 0 -> buf0
        stage(1, BK);                          // tile 1 -> buf1
        for (int t = 0; t < nk; t++) {
            const int cur = t & 1;
            // tile t landed (its 4 loads are the oldest); keep tile t+1's
            // 4 loads in flight.  Last tile: drain all.
            if (t + 1 < nk)
                asm volatile("s_waitcnt vmcnt(4)\n\ts_barrier" ::: "memory");
            else
                asm volatile("s_waitcnt vmcnt(0)\n\ts_barrier" ::: "memory");

            bf16x8 af[4], bfv[4];
#pragma unroll
            for (int i = 0; i < 4; i++)
                af[i] = *(const bf16x8*)&As[cur][(wm + i * 16 + l15) * BK + l4 * 8];
#pragma unroll
            for (int j = 0; j < 4; j++)
                bfv[j] = *(const bf16x8*)&Bs[cur][(wn + j * 16 + l15) * BK + l4 * 8];
#pragma unroll
            for (int i = 0; i < 4; i++)
#pragma unroll
                for (int j = 0; j < 4; j++)
                    acc[i][j] = __builtin_amdgcn_mfma_f32_16x16x32_bf16(af[i], bfv[j], acc[i][j], 0, 0, 0);

            // all waves' reads of buf cur complete -> safe to overwrite it
            asm volatile("s_waitcnt lgkmcnt(0)\n\ts_barrier" ::: "memory");
            if (t + 2 < nk) stage(cur, (t + 2) * BK);   // tile t+2 -> buf cur
        }
    } else {
        for (int k0 = 0; k0 < K; k0 += BK) {
            bf16x8 av[2], bv[2];
#pragma unroll
            for (int q = 0; q < 2; q++) {
                av[q] = ld8<AF32>(Ap, (size_t)(tm + srow + q * 64) * K + k0 + scol);
                bv[q] = ld8<BF32>(Bp, (size_t)(tn + srow + q * 64) * K + k0 + scol);
            }
            __syncthreads();
#pragma unroll
            for (int q = 0; q < 2; q++) {
                *(bf16x8*)&As[0][(srow + q * 64) * BK + scol] = av[q];
                *(bf16x8*)&Bs[0][(srow + q * 64) * BK + scol] = bv[q];
            }
            __syncthreads();

            bf16x8 af[4], bfv[4];
#pragma unroll
            for (int i = 0; i < 4; i++)
                af[i] = *(const bf16x8*)&As[0][(wm + i * 16 + l15) * BK + l4 * 8];
#pragma unroll
            for (int j = 0; j < 4; j++)
                bfv[j] = *(const bf16x8*)&Bs[0][(wn + j * 16 + l15) * BK + l4 * 8];
#pragma unroll
            for (int i = 0; i < 4; i++)
#pragma unroll
                for (int j = 0; j < 4; j++)
                    acc[i][j] = __builtin_amdgcn_mfma_f32_16x16x32_bf16(af[i], bfv[j], acc[i][j], 0, 0, 0);
        }
    }

#pragma unroll
    for (int i = 0; i < 4; i++)
#pragma unroll
        for (int j = 0; j < 4; j++) {
            if constexpr (CF32) {
#pragma unroll
                for (int r = 0; r < 4; r++) {
                    int row = tm + wm + i * 16 + l4 * 4 + r;
                    int col = tn + wn + j * 16 + l15;
                    ((float*)Cp)[(size_t)row * N + col] = acc[i][j][r];
                }
            } else {
                u16 v4[4];
#pragma unroll
                for (int r = 0; r < 4; r++) v4[r] = f2bf(acc[i][j][r]);
#pragma unroll
                for (int r = 0; r < 4; r++) {
                    int row = tm + wm + i * 16 + l4 * 4 + r;
                    int col = tn + wn + j * 16 + l15;
                    ((u16*)Cp)[(size_t)row * N + col] = v4[r];
                }
                if constexpr (WVT) {
                    if (tn >= 2048) {          // V-region tile (block-uniform)
                        int row0 = tm + wm + i * 16 + l4 * 4;   // mult of 4
                        int colv = tn + wn + j * 16 + l15 - 2048;
                        int bh = (row0 >> 11) * 16 + (colv >> 6);
                        int dh = colv & 63;
                        int t  = row0 & 2047;
                        u16x4 w = {v4[0], v4[1], v4[2], v4[3]};
                        *(u16x4*)&vtp[(size_t)bh * 131072 + (size_t)dh * 2048 + t] = w;
                    }
                }
            }
        }
}

// ---------------------------------------------------------------------------
// Flash attention, causal, no online rescaling (scores bounded). Verified
// r5/r8 structure (74.6 us, 0 bank conflicts): single-buffer KP/Vt/PB,
// reg-staged K/V (T14), MFMA row-sum denominator, HW bf16 casts, T5 setprio.
// FROZEN (three restructures r3/r6-r7/r9 all regressed vs this).
// ---------------------------------------------------------------------------
template <bool USE_VT>
__global__ __launch_bounds__(256) void attn2(const u16* __restrict__ qkv,
                                             const u16* __restrict__ vT,
                                             u16* __restrict__ y) {
    const int T = 2048, CW = 3072;
    __shared__ alignas(16) u16 KP[64 * 64];   // K tile [key][dh]
    __shared__ alignas(16) u16 Vt[64 * 64];   // V^T tile [dh][key]
    __shared__ alignas(16) u16 PB[64 * 64];   // P tile [qrow][key], wave-private rows

    const int tid  = threadIdx.x;
    const int lane = tid & 63;
    const int wave = tid >> 6;
    const int l15 = lane & 15;
    const int l4  = lane >> 4;

    const int bh = blockIdx.x;
    const int qt = 31 - blockIdx.y;            // heavy tiles dispatched first
    const int b = bh >> 4, h = bh & 15;
    const int q0 = qt * 64;

    const size_t base = (size_t)b * T * CW + h * 64;
    const u16* qp = qkv + base;
    const u16* kp = qkv + base + 1024;
    const u16* vp = qkv + base + 2048;
    const u16* vtp = USE_VT ? (vT + (size_t)bh * 131072) : nullptr;

    bf16x8 qf[2];
    {
        int qrow = q0 + wave * 16 + l15;
        qf[0] = *(const bf16x8*)&qp[(size_t)qrow * CW + l4 * 8];
        qf[1] = *(const bf16x8*)&qp[(size_t)qrow * CW + 32 + l4 * 8];
    }

    // all-ones B-fragment for the denominator MFMA
    bf16x8 ones;
#pragma unroll
    for (int i = 0; i < 8; i++) ones[i] = (__bf16)1.0f;

    const float C2 = 0.18033688f;              // (1/8) * log2(e)
    floatx4 Lacc = fzero();                    // rowsum accumulator
    floatx4 Oacc[4];
#pragma unroll
    for (int cf = 0; cf < 4; cf++) Oacc[cf] = fzero();

    const int sr = tid >> 3;                   // 0..31 (staging row)
    const int sc = tid & 7;                    // 0..7  (staging 16B chunk)

    bf16x8 kreg[2], vreg[2];
    auto stage_load = [&](int kt) {
        const int t0 = kt * 64;
#pragma unroll
        for (int p = 0; p < 2; p++)
            kreg[p] = *(const bf16x8*)&kp[(size_t)(t0 + sr + p * 32) * CW + sc * 8];
        if constexpr (USE_VT) {
#pragma unroll
            for (int p = 0; p < 2; p++)
                vreg[p] = *(const bf16x8*)&vtp[(size_t)(sr + p * 32) * 2048 + t0 + sc * 8];
        } else {
            const int dh = tid & 63;
            const int tb = wave * 8;
#pragma unroll
            for (int p = 0; p < 2; p++) {
                union { u16 u[8]; bf16x8 v; } tmp;
#pragma unroll
                for (int i = 0; i < 8; i++)
                    tmp.u[i] = vp[(size_t)(t0 + tb + p * 32 + i) * CW + dh];
                vreg[p] = tmp.v;
            }
        }
    };

    stage_load(0);

    for (int kt = 0; kt <= qt; kt++) {
        const int t0 = kt * 64;
        __syncthreads();                       // all waves' KP/Vt reads of prev tile done

        // commit staged K/V (compiler waits vmcnt before these ds_writes)
#pragma unroll
        for (int p = 0; p < 2; p++)
            *(bf16x8*)swz_ptr(KP, sr + p * 32, sc * 8) = kreg[p];
        if constexpr (USE_VT) {
#pragma unroll
            for (int p = 0; p < 2; p++)
                *(bf16x8*)swz_ptr(Vt, sr + p * 32, sc * 8) = vreg[p];
        } else {
            const int dh = tid & 63;
            const int tb = wave * 8;
#pragma unroll
            for (int p = 0; p < 2; p++)
                *(bf16x8*)swz_ptr(Vt, dh, tb + p * 32) = vreg[p];
        }
        __syncthreads();

        if (kt < qt) stage_load(kt + 1);       // prefetch next tile under compute

        // S = Q*K^T, per 16-key block: mask, exp2, P-store (short live ranges)
#pragma unroll
        for (int j = 0; j < 4; j++) {
            bf16x8 k0f = *(const bf16x8*)swz_ptr(KP, j * 16 + l15, l4 * 8);
            bf16x8 k1f = *(const bf16x8*)swz_ptr(KP, j * 16 + l15, 32 + l4 * 8);
            floatx4 s = fzero();
            s = __builtin_amdgcn_mfma_f32_16x16x32_bf16(qf[0], k0f, s, 0, 0, 0);
            s = __builtin_amdgcn_mfma_f32_16x16x32_bf16(qf[1], k1f, s, 0, 0, 0);
            float pj[4];
            if (kt == qt) {
#pragma unroll
                for (int r = 0; r < 4; r++) {
                    int qrow = q0 + wave * 16 + l4 * 4 + r;
                    int krow = t0 + j * 16 + l15;
                    float e = (krow <= qrow) ? s[r] * C2 : -1.0e30f;
                    pj[r] = EXP2F(e);
                }
            } else {
#pragma unroll
                for (int r = 0; r < 4; r++) pj[r] = EXP2F(s[r] * C2);
            }
            // wave-private rows; same-wave DS ordering -> no barrier needed
#pragma unroll
            for (int r = 0; r < 4; r++)
                *swz_ptr(PB, wave * 16 + l4 * 4 + r, j * 16 + l15) = f2bf(pj[r]);
        }

        // P A-frags (this wave's own 16 rows) + denominator + PV (T5 cluster)
        bf16x8 pf0 = *(const bf16x8*)swz_ptr(PB, wave * 16 + l15, l4 * 8);
        bf16x8 pf1 = *(const bf16x8*)swz_ptr(PB, wave * 16 + l15, 32 + l4 * 8);
        __builtin_amdgcn_s_setprio(1);
        Lacc = __builtin_amdgcn_mfma_f32_16x16x32_bf16(pf0, ones, Lacc, 0, 0, 0);
        Lacc = __builtin_amdgcn_mfma_f32_16x16x32_bf16(pf1, ones, Lacc, 0, 0, 0);
#pragma unroll
        for (int cf = 0; cf < 4; cf++) {
            bf16x8 v0f = *(const bf16x8*)swz_ptr(Vt, cf * 16 + l15, l4 * 8);
            bf16x8 v1f = *(const bf16x8*)swz_ptr(Vt, cf * 16 + l15, 32 + l4 * 8);
            Oacc[cf] = __builtin_amdgcn_mfma_f32_16x16x32_bf16(pf0, v0f, Oacc[cf], 0, 0, 0);
            Oacc[cf] = __builtin_amdgcn_mfma_f32_16x16x32_bf16(pf1, v1f, Oacc[cf], 0, 0, 0);
        }
        __builtin_amdgcn_s_setprio(0);
    }

    // epilogue: Lacc[r] already holds the full row sum in every lane column
#pragma unroll
    for (int r = 0; r < 4; r++) {
        float inv = 1.0f / Lacc[r];
        int qrow = q0 + wave * 16 + l4 * 4 + r;
        size_t orow = ((size_t)b * T + qrow) * 1024 + h * 64;
#pragma unroll
        for (int cf = 0; cf < 4; cf++)
            y[orow + cf * 16 + l15] = f2bf(Oacc[cf][r] * inv);
    }
}

extern "C" void kernel_launch(void* const* d_in, const int* in_sizes, int n_in,
                              void* d_out, int out_size, void* d_ws, size_t ws_size,
                              hipStream_t stream) {
    const float* x      = (const float*)d_in[0];   // [8192,1024] fp32
    const float* w_attn = (const float*)d_in[1];   // [3072,1024] fp32
    const float* w_proj = (const float*)d_in[2];   // [1024,1024] fp32
    float* out = (float*)d_out;                    // [8192,1024] fp32

    const size_t QKV = (size_t)8192 * 3072;
    const size_t Y   = (size_t)8192 * 1024;
    const size_t VTE = (size_t)64 * 64 * 2048;     // 8.4M
    const size_t XB  = (size_t)8192 * 1024;
    const size_t WAB = (size_t)3072 * 1024;
    const size_t WPB = (size_t)1024 * 1024;

    u16* qkv = (u16*)d_ws;
    u16* yb  = qkv + QKV;

    const bool full = ws_size >= (QKV + Y + VTE + XB + WAB + WPB) * sizeof(u16); // 104 MiB
    if (ws_size < (QKV + Y) * sizeof(u16)) return;                               // 64 MiB floor

    dim3 blk(256);
    dim3 g1(3072 / 128, 8192 / 128), g2(1024 / 128, 8192 / 128);   // nwg: 1536, 512 (both %8==0)
    dim3 ga(64, 32);

    if (full) {
        u16* vT  = yb + Y;
        u16* xb  = vT + VTE;                       // xb|wab|wpb contiguous
        cvt_all<<<6144, blk, 0, stream>>>(x, w_attn, w_proj, xb);
        u16* wab = xb + XB;
        u16* wpb = wab + WAB;
        // gemm1 writes qkv AND the transposed V copy (fused transpose_v)
        gemm_bt<false, false, false, true><<<g1, blk, 0, stream>>>(xb, wab, qkv, vT, 8192, 3072, 1024);
        attn2<true><<<ga, blk, 0, stream>>>(qkv, vT, yb);
        gemm_bt<false, false, true, false><<<g2, blk, 0, stream>>>(yb, wpb, out, nullptr, 8192, 1024, 1024);
    } else {
        gemm_bt<true, true, false, false><<<g1, blk, 0, stream>>>(x, w_attn, qkv, nullptr, 8192, 3072, 1024);
        attn2<false><<<ga, blk, 0, stream>>>(qkv, nullptr, yb);
        gemm_bt<false, true, true, false><<<g2, blk, 0, stream>>>(yb, w_proj, out, nullptr, 8192, 1024, 1024);
    }
}